// Round 5
// baseline (785.476 us; speedup 1.0000x reference)
//
#include <hip/hip_runtime.h>

// Problem constants (from reference)
#define N_NODES 20000
#define F_IN    512
#define D_H     256
#define E_EDGES 200000
#define L_LAYERS 3
#define T_ETYPES 2

typedef __attribute__((ext_vector_type(8))) short bf16x8;
typedef __attribute__((ext_vector_type(4))) float f32x4;

__device__ __forceinline__ unsigned short f2b(float f) {
    unsigned int u = __float_as_uint(f);
    u = (u + 0x7FFFu + ((u >> 16) & 1u)) >> 16;   // round-nearest-even
    return (unsigned short)u;
}
__device__ __forceinline__ unsigned int pack2(float a, float b) {
    return (unsigned int)f2b(a) | ((unsigned int)f2b(b) << 16);
}

// ---------------- bf16 MFMA GEMM (lin / pool) ----------------
// C[M, NOUT slice] = act(A @ W^T + bias). Block 64x128, 4 waves 2x2, wave 32x64.
// LDS fragment order: per 16x32 tile, elem (n,k) at tile*512 + ((k>>3)*16+(n&15))*8 + (k&7)
template <int A_FP32>
__global__ __launch_bounds__(256) void gemm_mfma(
    const void* __restrict__ Ap, const unsigned short* __restrict__ W,
    const float* __restrict__ bias, unsigned short* __restrict__ Cout,
    int M, int K, int ldc, int relu)
{
    __shared__ unsigned short sA[64 * 32];
    __shared__ unsigned short sB[128 * 32];
    const int tid  = threadIdx.x;
    const int lane = tid & 63;
    const int w    = tid >> 6;
    const int wm   = w >> 1, wn = w & 1;
    const int bm   = blockIdx.y * 64;
    const int bn   = blockIdx.x * 128;

    const int sma = tid >> 2, qa = tid & 3;
    const int aoff = ((sma >> 4) << 9) + ((qa * 16 + (sma & 15)) << 3);
    const int arow = min(bm + sma, M - 1);
    const int snb = tid >> 1, hb = tid & 1;
    const int boff0 = ((snb >> 4) << 9) + (((hb * 2 + 0) * 16 + (snb & 15)) << 3);
    const int boff1 = ((snb >> 4) << 9) + (((hb * 2 + 1) * 16 + (snb & 15)) << 3);
    const unsigned short* bPtr = W + (size_t)(bn + snb) * K + hb * 16;

    f32x4 acc[2][4] = {};

    for (int k0 = 0; k0 < K; k0 += 32) {
        uint4 av;
        if (A_FP32) {
            const float* aPtrF = (const float*)Ap + (size_t)arow * K + qa * 8 + k0;
            const float4 f0 = *(const float4*)(aPtrF);
            const float4 f1 = *(const float4*)(aPtrF + 4);
            av.x = pack2(f0.x, f0.y); av.y = pack2(f0.z, f0.w);
            av.z = pack2(f1.x, f1.y); av.w = pack2(f1.z, f1.w);
        } else {
            av = *(const uint4*)((const unsigned short*)Ap + (size_t)arow * K + qa * 8 + k0);
        }
        const uint4 bv0 = *(const uint4*)(bPtr + k0);
        const uint4 bv1 = *(const uint4*)(bPtr + k0 + 8);
        __syncthreads();
        *(uint4*)(sA + aoff)  = av;
        *(uint4*)(sB + boff0) = bv0;
        *(uint4*)(sB + boff1) = bv1;
        __syncthreads();
        bf16x8 af[2], bf[4];
#pragma unroll
        for (int i = 0; i < 2; ++i)
            af[i] = *(const bf16x8*)(sA + ((wm * 2 + i) << 9) + lane * 8);
#pragma unroll
        for (int j = 0; j < 4; ++j)
            bf[j] = *(const bf16x8*)(sB + ((wn * 4 + j) << 9) + lane * 8);
#pragma unroll
        for (int i = 0; i < 2; ++i)
#pragma unroll
            for (int j = 0; j < 4; ++j)
                acc[i][j] = __builtin_amdgcn_mfma_f32_16x16x32_bf16(
                    af[i], bf[j], acc[i][j], 0, 0, 0);
    }

    const int cbase = bn + wn * 64 + (lane & 15);
    const int rbase = bm + wm * 32 + ((lane >> 4) << 2);
#pragma unroll
    for (int j = 0; j < 4; ++j) {
        const int col = cbase + j * 16;
        const float bj = bias[col];
#pragma unroll
        for (int i = 0; i < 2; ++i)
#pragma unroll
            for (int r = 0; r < 4; ++r) {
                const int row = rbase + i * 16 + r;
                if (row < M) {
                    float v = acc[i][j][r] + bj;
                    if (relu) v = fmaxf(v, 0.f);
                    Cout[(size_t)row * ldc + col] = f2b(v);
                }
            }
    }
}

// ---------------- fused SAGE layer tail: both etypes, dual GEMM + ReLU + LN + sum ----
// out[row] = sum_t LN_t( maybe_relu( h@Wself_t^T + neigh_t@Wneigh_t^T + b_t ) )
// Block 32 rows x 256 cols, 4 waves 1x4 (wave = 32x64). Grid = M/32 = 625 (exact).
template <int OUT_FP32>
__global__ __launch_bounds__(256) void sage_dual_ln(
    const unsigned short* __restrict__ h,      // [M,256] bf16
    const unsigned short* __restrict__ neigh,  // [M,512] bf16 (t*256 col offset)
    const unsigned short* __restrict__ Ws,     // [2,256,256] bf16
    const unsigned short* __restrict__ Wn,     // [2,256,256] bf16
    const float* __restrict__ bias2,           // [2,256]
    const float* __restrict__ gamma2,          // [2,256]
    const float* __restrict__ beta2,           // [2,256]
    void* __restrict__ outp, int relu)
{
    __shared__ unsigned short sA[2][32 * 32];
    __shared__ unsigned short sB[2][256 * 32];
    __shared__ float sS[2][4][32], sQ[2][4][32];
    const int tid  = threadIdx.x;
    const int lane = tid & 63;
    const int wn   = tid >> 6;            // wave = column group
    const int bm   = blockIdx.x * 32;

    // A staging map: (half, i2): i2 0..127 -> (row ar 0..31, quarter aq 0..3)
    const int half = tid >> 7;
    const int i2   = tid & 127;
    const int ar   = i2 >> 2, aq = i2 & 3;
    const int aoff = ((ar >> 4) << 9) + ((aq * 16 + (ar & 15)) << 3);
    // B staging: row nb = tid (0..255)
    const int nb = tid;
    const int bso = ((nb >> 4) << 9) + ((nb & 15) << 3);  // + (kg*16)<<3 per kg

    f32x4 acc[2][2][4] = {};  // [etype][mtile][ntile]

    // ---- self passes: A = h (staged once, used for both etypes' weights) ----
    {
        const unsigned short* aPtr  = h + (size_t)(bm + ar) * D_H + aq * 8;
        const unsigned short* bPtr0 = Ws + (size_t)nb * D_H;
        const unsigned short* bPtr1 = Ws + 65536 + (size_t)nb * D_H;
        for (int k0 = 0; k0 < D_H; k0 += 32) {
            uint4 av;
            if (half == 0) av = *(const uint4*)(aPtr + k0);
            uint4 bv0[4], bv1[4];
#pragma unroll
            for (int kg = 0; kg < 4; ++kg) {
                bv0[kg] = *(const uint4*)(bPtr0 + k0 + kg * 8);
                bv1[kg] = *(const uint4*)(bPtr1 + k0 + kg * 8);
            }
            __syncthreads();
            if (half == 0) *(uint4*)(sA[0] + aoff) = av;
#pragma unroll
            for (int kg = 0; kg < 4; ++kg) {
                *(uint4*)(sB[0] + bso + (kg << 7)) = bv0[kg];
                *(uint4*)(sB[1] + bso + (kg << 7)) = bv1[kg];
            }
            __syncthreads();
            bf16x8 af[2];
#pragma unroll
            for (int i = 0; i < 2; ++i)
                af[i] = *(const bf16x8*)(sA[0] + (i << 9) + lane * 8);
#pragma unroll
            for (int e = 0; e < 2; ++e)
#pragma unroll
                for (int j = 0; j < 4; ++j) {
                    const bf16x8 bf = *(const bf16x8*)(sB[e] + ((wn * 4 + j) << 9) + lane * 8);
#pragma unroll
                    for (int i = 0; i < 2; ++i)
                        acc[e][i][j] = __builtin_amdgcn_mfma_f32_16x16x32_bf16(
                            af[i], bf, acc[e][i][j], 0, 0, 0);
                }
        }
    }

    // ---- neigh passes: A_e = neigh[:, e*256 + k] ----
    {
        const unsigned short* aPtr  = neigh + (size_t)(bm + ar) * 512 + half * D_H + aq * 8;
        const unsigned short* bPtr0 = Wn + (size_t)nb * D_H;
        const unsigned short* bPtr1 = Wn + 65536 + (size_t)nb * D_H;
        for (int k0 = 0; k0 < D_H; k0 += 32) {
            const uint4 av = *(const uint4*)(aPtr + k0);
            uint4 bv0[4], bv1[4];
#pragma unroll
            for (int kg = 0; kg < 4; ++kg) {
                bv0[kg] = *(const uint4*)(bPtr0 + k0 + kg * 8);
                bv1[kg] = *(const uint4*)(bPtr1 + k0 + kg * 8);
            }
            __syncthreads();
            *(uint4*)(sA[half] + aoff) = av;
#pragma unroll
            for (int kg = 0; kg < 4; ++kg) {
                *(uint4*)(sB[0] + bso + (kg << 7)) = bv0[kg];
                *(uint4*)(sB[1] + bso + (kg << 7)) = bv1[kg];
            }
            __syncthreads();
#pragma unroll
            for (int e = 0; e < 2; ++e) {
                bf16x8 af[2];
#pragma unroll
                for (int i = 0; i < 2; ++i)
                    af[i] = *(const bf16x8*)(sA[e] + (i << 9) + lane * 8);
#pragma unroll
                for (int j = 0; j < 4; ++j) {
                    const bf16x8 bf = *(const bf16x8*)(sB[e] + ((wn * 4 + j) << 9) + lane * 8);
#pragma unroll
                    for (int i = 0; i < 2; ++i)
                        acc[e][i][j] = __builtin_amdgcn_mfma_f32_16x16x32_bf16(
                            af[i], bf, acc[e][i][j], 0, 0, 0);
                }
            }
        }
    }

    // ---- epilogue: per-etype LN stats (wave partial -> LDS combine), sum, write ----
    const int colb = wn * 64 + (lane & 15);
    const int rq   = (lane >> 4) << 2;   // 0,4,8,12
    float bia[2][4], gam[2][4], bet[2][4];
#pragma unroll
    for (int e = 0; e < 2; ++e)
#pragma unroll
        for (int j = 0; j < 4; ++j) {
            const int col = colb + j * 16;
            bia[e][j] = bias2[e * D_H + col];
            gam[e][j] = gamma2[e * D_H + col];
            bet[e][j] = beta2[e * D_H + col];
        }
#pragma unroll
    for (int e = 0; e < 2; ++e)
#pragma unroll
        for (int i = 0; i < 2; ++i)
#pragma unroll
            for (int r = 0; r < 4; ++r) {
                float s = 0.f, q = 0.f;
#pragma unroll
                for (int j = 0; j < 4; ++j) {
                    float v = acc[e][i][j][r] + bia[e][j];
                    if (relu) v = fmaxf(v, 0.f);
                    s += v; q += v * v;
                }
#pragma unroll
                for (int o = 1; o < 16; o <<= 1) {
                    s += __shfl_xor(s, o);
                    q += __shfl_xor(q, o);
                }
                if ((lane & 15) == 0) {
                    sS[e][wn][i * 16 + rq + r] = s;
                    sQ[e][wn][i * 16 + rq + r] = q;
                }
            }
    __syncthreads();
#pragma unroll
    for (int i = 0; i < 2; ++i)
#pragma unroll
        for (int r = 0; r < 4; ++r) {
            const int rl = i * 16 + rq + r;
            const int row = bm + rl;
            float mean[2], inv[2];
#pragma unroll
            for (int e = 0; e < 2; ++e) {
                const float st = sS[e][0][rl] + sS[e][1][rl] + sS[e][2][rl] + sS[e][3][rl];
                const float qt = sQ[e][0][rl] + sQ[e][1][rl] + sQ[e][2][rl] + sQ[e][3][rl];
                mean[e] = st * (1.f / 256.f);
                const float var = qt * (1.f / 256.f) - mean[e] * mean[e];
                inv[e] = rsqrtf(var + 1e-5f);
            }
#pragma unroll
            for (int j = 0; j < 4; ++j) {
                const int col = colb + j * 16;
                float o = 0.f;
#pragma unroll
                for (int e = 0; e < 2; ++e) {
                    float v = acc[e][i][j][r] + bia[e][j];
                    if (relu) v = fmaxf(v, 0.f);
                    o += (v - mean[e]) * inv[e] * gam[e][j] + bet[e][j];
                }
                if (OUT_FP32)
                    ((float*)outp)[(size_t)row * D_H + col] = o;
                else
                    ((unsigned short*)outp)[(size_t)row * D_H + col] = f2b(o);
            }
        }
}

// ---------------- weight fp32 -> bf16 (4 arrays, one dispatch) ----------------
__global__ __launch_bounds__(256) void f2b4_kernel(
    const float* __restrict__ s0, unsigned short* __restrict__ d0, int n0,
    const float* __restrict__ s1, unsigned short* __restrict__ d1, int n1,
    const float* __restrict__ s2, unsigned short* __restrict__ d2, int n2,
    const float* __restrict__ s3, unsigned short* __restrict__ d3, int n3)
{
    int i = blockIdx.x * 256 + threadIdx.x;
    const float* s; unsigned short* d;
    if (i < n0) { s = s0; d = d0; }
    else if ((i -= n0) < n1) { s = s1; d = d1; }
    else if ((i -= n1) < n2) { s = s2; d = d2; }
    else if ((i -= n2) < n3) { s = s3; d = d3; }
    else return;
    const float4 v = ((const float4*)s)[i];
    ((ushort4*)d)[i] = make_ushort4(f2b(v.x), f2b(v.y), f2b(v.z), f2b(v.w));
}

// ---------------- CSR build (both etypes batched; once per launch) ----------------
__global__ __launch_bounds__(256) void zero_int_kernel(int* p, int n)
{
    int i = blockIdx.x * 256 + threadIdx.x;
    if (i < n) p[i] = 0;
}

__global__ __launch_bounds__(256) void count_deg_kernel(
    const int* __restrict__ dst, int* __restrict__ cnt, int E2)
{
    int e = blockIdx.x * 256 + threadIdx.x;
    if (e < E2) {
        const int base = (e >= E_EDGES) ? N_NODES : 0;
        atomicAdd(&cnt[base + dst[e]], 1);
    }
}

__global__ __launch_bounds__(256) void scanA_kernel(
    const int* __restrict__ cnt, int* __restrict__ incl, int* __restrict__ bsum, int n)
{
    __shared__ int tmp[256];
    const int tid = threadIdx.x;
    const int i = blockIdx.x * 256 + tid;
    const int v = (i < n) ? cnt[i] : 0;
    tmp[tid] = v;
    __syncthreads();
#pragma unroll
    for (int o = 1; o < 256; o <<= 1) {
        const int t = (tid >= o) ? tmp[tid - o] : 0;
        __syncthreads();
        tmp[tid] += t;
        __syncthreads();
    }
    if (i < n) incl[i] = tmp[tid];
    if (tid == 255) bsum[blockIdx.x] = tmp[255];
}

__global__ __launch_bounds__(256) void scanB_kernel(int* __restrict__ bsum, int nb)
{
    __shared__ int tmp[256];
    const int tid = threadIdx.x;
    const int v = (tid < nb) ? bsum[tid] : 0;
    tmp[tid] = v;
    __syncthreads();
#pragma unroll
    for (int o = 1; o < 256; o <<= 1) {
        const int t = (tid >= o) ? tmp[tid - o] : 0;
        __syncthreads();
        tmp[tid] += t;
        __syncthreads();
    }
    if (tid < nb) bsum[tid] = tmp[tid] - v;  // exclusive
}

__global__ __launch_bounds__(256) void scanC_kernel(
    const int* __restrict__ cnt, const int* __restrict__ incl,
    const int* __restrict__ bsum, int* __restrict__ off, int* __restrict__ cursor, int n)
{
    const int i = blockIdx.x * 256 + threadIdx.x;
    if (i < n) {
        const int e = incl[i] + bsum[blockIdx.x];
        off[i + 1] = e;
        cursor[i] = e - cnt[i];
    }
    if (i == 0) off[0] = 0;
}

__global__ __launch_bounds__(256) void fill_csr_kernel(
    const int* __restrict__ src, const int* __restrict__ dst,
    int* __restrict__ cursor, int* __restrict__ esrc, int E2)
{
    int e = blockIdx.x * 256 + threadIdx.x;
    if (e < E2) {
        const int base = (e >= E_EDGES) ? N_NODES : 0;
        const int pos = atomicAdd(&cursor[base + dst[e]], 1);
        esrc[pos] = src[e];
    }
}

// ---------------- segment max (bf16, both etypes): one wave per (node,t) ----------------
__device__ __forceinline__ ushort4 umax4(ushort4 a, ushort4 b)
{
    a.x = a.x > b.x ? a.x : b.x;
    a.y = a.y > b.y ? a.y : b.y;
    a.z = a.z > b.z ? a.z : b.z;
    a.w = a.w > b.w ? a.w : b.w;
    return a;
}

__global__ __launch_bounds__(256) void seg_max_kernel(
    const unsigned short* __restrict__ hp, const int* __restrict__ off,
    const int* __restrict__ esrc, unsigned short* __restrict__ neigh)
{
    const int g = blockIdx.x * 4 + (threadIdx.x >> 6);
    if (g >= 2 * N_NODES) return;
    const int t = (g >= N_NODES) ? 1 : 0;
    const int node = g - t * N_NODES;
    const int lane = threadIdx.x & 63;
    const int co = t * D_H + lane * 4;
    const int e0 = off[g], e1 = off[g + 1];
    ushort4 acc = make_ushort4(0, 0, 0, 0);
    int e = e0;
    for (; e + 4 <= e1; e += 4) {
        const int s0 = esrc[e + 0], s1 = esrc[e + 1];
        const int s2 = esrc[e + 2], s3 = esrc[e + 3];
        const ushort4 v0 = *(const ushort4*)(hp + (size_t)s0 * 512 + co);
        const ushort4 v1 = *(const ushort4*)(hp + (size_t)s1 * 512 + co);
        const ushort4 v2 = *(const ushort4*)(hp + (size_t)s2 * 512 + co);
        const ushort4 v3 = *(const ushort4*)(hp + (size_t)s3 * 512 + co);
        acc = umax4(umax4(umax4(acc, v0), umax4(v1, v2)), v3);
    }
    for (; e < e1; ++e)
        acc = umax4(acc, *(const ushort4*)(hp + (size_t)esrc[e] * 512 + co));
    *(ushort4*)(neigh + (size_t)node * 512 + co) = acc;
}

extern "C" void kernel_launch(void* const* d_in, const int* in_sizes, int n_in,
                              void* d_out, int out_size, void* d_ws, size_t ws_size,
                              hipStream_t stream)
{
    const float* x      = (const float*)d_in[0];
    const int*   src    = (const int*)d_in[1];
    const int*   dst    = (const int*)d_in[2];
    const float* Wlin   = (const float*)d_in[3];
    const float* blin   = (const float*)d_in[4];
    const float* Wpool  = (const float*)d_in[5];
    const float* bpool  = (const float*)d_in[6];
    const float* Wself  = (const float*)d_in[7];
    const float* Wneigh = (const float*)d_in[8];
    const float* bconv  = (const float*)d_in[9];
    const float* gamma  = (const float*)d_in[10];
    const float* beta   = (const float*)d_in[11];

    const size_t NB = (size_t)N_NODES * D_H;  // 5.12M
    char* p = (char*)d_ws;
    unsigned short* hp_b    = (unsigned short*)p; p += NB * 2 * T_ETYPES;  // [N,512]
    unsigned short* neigh_b = (unsigned short*)p; p += NB * 2 * T_ETYPES;  // [N,512]
    unsigned short* h_a     = (unsigned short*)p; p += NB * 2;
    unsigned short* h_b     = (unsigned short*)p; p += NB * 2;
    unsigned short* wlin_b  = (unsigned short*)p; p += (size_t)D_H * F_IN * 2;
    const size_t WSZ = (size_t)L_LAYERS * T_ETYPES * D_H * D_H;
    unsigned short* wpool_b = (unsigned short*)p; p += WSZ * 2;
    unsigned short* wself_b = (unsigned short*)p; p += WSZ * 2;
    unsigned short* wneigh_b= (unsigned short*)p; p += WSZ * 2;
    int* ip = (int*)p;
    const int NT = T_ETYPES * N_NODES;  // 40000
    int* cnt    = ip; ip += NT;
    int* incl   = ip; ip += NT;
    int* off    = ip; ip += NT + 1;
    int* cursor = ip; ip += NT;
    int* esrc   = ip; ip += T_ETYPES * E_EDGES;
    int* bsum   = ip; ip += 256;

    const dim3 blk(256);
    const int E2 = T_ETYPES * E_EDGES;
    const dim3 e2grid((E2 + 255) / 256);
    const dim3 ntgrid((NT + 255) / 256);
    const int nScanBlk = (NT + 255) / 256;  // 157

    // ---- weights -> bf16 (one dispatch) ----
    {
        const int n0 = D_H * F_IN / 4, nw = (int)(WSZ / 4);
        const int tot = n0 + 3 * nw;
        f2b4_kernel<<<dim3((tot + 255) / 256), blk, 0, stream>>>(
            Wlin, wlin_b, n0, Wpool, wpool_b, nw, Wself, wself_b, nw, Wneigh, wneigh_b, nw);
    }

    // ---- CSR build, both etypes batched ----
    zero_int_kernel<<<ntgrid, blk, 0, stream>>>(cnt, NT);
    count_deg_kernel<<<e2grid, blk, 0, stream>>>(dst, cnt, E2);
    scanA_kernel<<<dim3(nScanBlk), blk, 0, stream>>>(cnt, incl, bsum, NT);
    scanB_kernel<<<dim3(1), blk, 0, stream>>>(bsum, nScanBlk);
    scanC_kernel<<<dim3(nScanBlk), blk, 0, stream>>>(cnt, incl, bsum, off, cursor, NT);
    fill_csr_kernel<<<e2grid, blk, 0, stream>>>(src, dst, cursor, esrc, E2);

    // ---- h0 = bf16(x @ Wlin^T + blin) : fp32 A fused-convert ----
    gemm_mfma<1><<<dim3(2, (N_NODES + 63) / 64), blk, 0, stream>>>(
        x, wlin_b, blin, h_a, N_NODES, F_IN, D_H, 0);

    unsigned short* h = h_a;
    unsigned short* hn = h_b;
    const dim3 pgrid(4, (N_NODES + 63) / 64);             // pool: N=512 batched over etypes
    const dim3 sgrid((2 * N_NODES + 3) / 4);
    const dim3 fgrid(N_NODES / 32);                       // 625, exact
    for (int l = 0; l < L_LAYERS; ++l) {
        const int relu = (l < L_LAYERS - 1) ? 1 : 0;
        const size_t wo = (size_t)l * T_ETYPES * D_H * D_H;
        const size_t bo = (size_t)l * T_ETYPES * D_H;
        // hp[:, t*256:] = bf16(relu(h @ Wpool[l,t]^T + bpool[l,t])), both t in one dispatch
        gemm_mfma<0><<<pgrid, blk, 0, stream>>>(
            h, wpool_b + wo, bpool + bo, hp_b, N_NODES, D_H, T_ETYPES * D_H, 1);
        // neigh = segment_max per (node, t)
        seg_max_kernel<<<sgrid, blk, 0, stream>>>(hp_b, off, esrc, neigh_b);
        // fused: both etypes' dual GEMM + relu + LN + sum
        if (l < L_LAYERS - 1) {
            sage_dual_ln<0><<<fgrid, blk, 0, stream>>>(
                h, neigh_b, wself_b + wo, wneigh_b + wo,
                bconv + bo, gamma + bo, beta + bo, hn, relu);
        } else {
            sage_dual_ln<1><<<fgrid, blk, 0, stream>>>(
                h, neigh_b, wself_b + wo, wneigh_b + wo,
                bconv + bo, gamma + bo, beta + bo, d_out, relu);
        }
        unsigned short* tmp = h; h = hn; hn = tmp;
    }
}

// Round 6
// 732.160 us; speedup vs baseline: 1.0728x; 1.0728x over previous
//
#include <hip/hip_runtime.h>

// Problem constants (from reference)
#define N_NODES 20000
#define F_IN    512
#define D_H     256
#define E_EDGES 200000
#define L_LAYERS 3
#define T_ETYPES 2

typedef __attribute__((ext_vector_type(8))) short bf16x8;
typedef __attribute__((ext_vector_type(4))) float f32x4;

__device__ __forceinline__ unsigned short f2b(float f) {
    unsigned int u = __float_as_uint(f);
    u = (u + 0x7FFFu + ((u >> 16) & 1u)) >> 16;   // round-nearest-even
    return (unsigned short)u;
}
__device__ __forceinline__ unsigned int pack2(float a, float b) {
    return (unsigned int)f2b(a) | ((unsigned int)f2b(b) << 16);
}

// ---------------- bf16 MFMA GEMM (lin / pool) ----------------
// C[M, NOUT slice] = act(A @ W^T + bias). Block 64x128, 4 waves 2x2, wave 32x64.
// LDS fragment order: per 16x32 tile, elem (n,k) at tile*512 + ((k>>3)*16+(n&15))*8 + (k&7)
template <int A_FP32>
__global__ __launch_bounds__(256) void gemm_mfma(
    const void* __restrict__ Ap, const unsigned short* __restrict__ W,
    const float* __restrict__ bias, unsigned short* __restrict__ Cout,
    int M, int K, int ldc, int relu)
{
    __shared__ unsigned short sA[64 * 32];
    __shared__ unsigned short sB[128 * 32];
    const int tid  = threadIdx.x;
    const int lane = tid & 63;
    const int w    = tid >> 6;
    const int wm   = w >> 1, wn = w & 1;
    const int bm   = blockIdx.y * 64;
    const int bn   = blockIdx.x * 128;

    const int sma = tid >> 2, qa = tid & 3;
    const int aoff = ((sma >> 4) << 9) + ((qa * 16 + (sma & 15)) << 3);
    const int arow = min(bm + sma, M - 1);
    const int snb = tid >> 1, hb = tid & 1;
    const int boff0 = ((snb >> 4) << 9) + (((hb * 2 + 0) * 16 + (snb & 15)) << 3);
    const int boff1 = ((snb >> 4) << 9) + (((hb * 2 + 1) * 16 + (snb & 15)) << 3);
    const unsigned short* bPtr = W + (size_t)(bn + snb) * K + hb * 16;

    f32x4 acc[2][4] = {};

    for (int k0 = 0; k0 < K; k0 += 32) {
        uint4 av;
        if (A_FP32) {
            const float* aPtrF = (const float*)Ap + (size_t)arow * K + qa * 8 + k0;
            const float4 f0 = *(const float4*)(aPtrF);
            const float4 f1 = *(const float4*)(aPtrF + 4);
            av.x = pack2(f0.x, f0.y); av.y = pack2(f0.z, f0.w);
            av.z = pack2(f1.x, f1.y); av.w = pack2(f1.z, f1.w);
        } else {
            av = *(const uint4*)((const unsigned short*)Ap + (size_t)arow * K + qa * 8 + k0);
        }
        const uint4 bv0 = *(const uint4*)(bPtr + k0);
        const uint4 bv1 = *(const uint4*)(bPtr + k0 + 8);
        __syncthreads();
        *(uint4*)(sA + aoff)  = av;
        *(uint4*)(sB + boff0) = bv0;
        *(uint4*)(sB + boff1) = bv1;
        __syncthreads();
        bf16x8 af[2], bf[4];
#pragma unroll
        for (int i = 0; i < 2; ++i)
            af[i] = *(const bf16x8*)(sA + ((wm * 2 + i) << 9) + lane * 8);
#pragma unroll
        for (int j = 0; j < 4; ++j)
            bf[j] = *(const bf16x8*)(sB + ((wn * 4 + j) << 9) + lane * 8);
#pragma unroll
        for (int i = 0; i < 2; ++i)
#pragma unroll
            for (int j = 0; j < 4; ++j)
                acc[i][j] = __builtin_amdgcn_mfma_f32_16x16x32_bf16(
                    af[i], bf[j], acc[i][j], 0, 0, 0);
    }

    const int cbase = bn + wn * 64 + (lane & 15);
    const int rbase = bm + wm * 32 + ((lane >> 4) << 2);
#pragma unroll
    for (int j = 0; j < 4; ++j) {
        const int col = cbase + j * 16;
        const float bj = bias[col];
#pragma unroll
        for (int i = 0; i < 2; ++i)
#pragma unroll
            for (int r = 0; r < 4; ++r) {
                const int row = rbase + i * 16 + r;
                if (row < M) {
                    float v = acc[i][j][r] + bj;
                    if (relu) v = fmaxf(v, 0.f);
                    Cout[(size_t)row * ldc + col] = f2b(v);
                }
            }
    }
}

// ---------------- fused layer tail, ONE etype: dual GEMM + ReLU + LN (+acc) ----------------
// o = LN( maybe_relu( h@Ws^T + neigh@Wn^T + bias ) )*gamma+beta  [+ partial]
// Block 32 rows x 256 cols (full LN row), 4 waves 1x4 (wave 32x64), acc[2][4]=32 VGPRs.
// Grid = M/32 = 625 exact. MODE 0: write fp32 partial. MODE 1: +partial, write bf16.
// MODE 2: +partial, write fp32.
template <int MODE>
__global__ __launch_bounds__(256) void sage_ln32(
    const unsigned short* __restrict__ h,      // [M,256] bf16
    const unsigned short* __restrict__ neigh,  // [M,512] bf16, caller adds t*256; ld=512
    const unsigned short* __restrict__ Ws,     // [256,256] bf16 (this etype)
    const unsigned short* __restrict__ Wn,     // [256,256] bf16
    const float* __restrict__ bias, const float* __restrict__ gamma,
    const float* __restrict__ beta, const float* __restrict__ pin,
    void* __restrict__ outp, int relu)
{
    __shared__ unsigned short sA[32 * 32];
    __shared__ unsigned short sB[256 * 32];
    __shared__ float sS[4][32], sQ[4][32];
    const int tid  = threadIdx.x;
    const int lane = tid & 63;
    const int wn   = tid >> 6;            // wave = 64-col group
    const int bm   = blockIdx.x * 32;

    // A staging: tid<128 -> (row ar 0..31, quarter aq 0..3), one uint4 (8 bf16)
    const int ar = (tid & 127) >> 2, aq = tid & 3;
    const int aoff = ((ar >> 4) << 9) + ((aq * 16 + (ar & 15)) << 3);
    // B staging: row nb = tid, 4 uint4 (kg=0..3)
    const int nb = tid;
    const int bso = ((nb >> 4) << 9) + ((nb & 15) << 3);

    f32x4 acc[2][4] = {};

    for (int pass = 0; pass < 2; ++pass) {
        const unsigned short* __restrict__ A = pass ? neigh : h;
        const int lda = pass ? (T_ETYPES * D_H) : D_H;
        const unsigned short* __restrict__ W = pass ? Wn : Ws;
        const unsigned short* aPtr = A + (size_t)(bm + ar) * lda + aq * 8;
        const unsigned short* bPtr = W + (size_t)nb * D_H;
        for (int k0 = 0; k0 < D_H; k0 += 32) {
            uint4 av;
            if (tid < 128) av = *(const uint4*)(aPtr + k0);
            uint4 bv[4];
#pragma unroll
            for (int kg = 0; kg < 4; ++kg)
                bv[kg] = *(const uint4*)(bPtr + k0 + kg * 8);
            __syncthreads();
            if (tid < 128) *(uint4*)(sA + aoff) = av;
#pragma unroll
            for (int kg = 0; kg < 4; ++kg)
                *(uint4*)(sB + bso + (kg << 7)) = bv[kg];
            __syncthreads();
            bf16x8 af[2];
#pragma unroll
            for (int i = 0; i < 2; ++i)
                af[i] = *(const bf16x8*)(sA + (i << 9) + lane * 8);
#pragma unroll
            for (int j = 0; j < 4; ++j) {
                const bf16x8 bf = *(const bf16x8*)(sB + ((wn * 4 + j) << 9) + lane * 8);
#pragma unroll
                for (int i = 0; i < 2; ++i)
                    acc[i][j] = __builtin_amdgcn_mfma_f32_16x16x32_bf16(
                        af[i], bf, acc[i][j], 0, 0, 0);
            }
        }
    }

    // Epilogue: per-row LN over 256 cols (wave partial over its 64 cols -> LDS combine).
    // C/D layout: col = lane&15 (+j*16), row = (lane>>4)*4 + r (+i*16)
    const int colb = wn * 64 + (lane & 15);
    const int rq   = (lane >> 4) << 2;
    float bia[4], gam[4], bet[4];
#pragma unroll
    for (int j = 0; j < 4; ++j) {
        const int col = colb + j * 16;
        bia[j] = bias[col]; gam[j] = gamma[col]; bet[j] = beta[col];
    }
#pragma unroll
    for (int i = 0; i < 2; ++i)
#pragma unroll
        for (int r = 0; r < 4; ++r) {
            float s = 0.f, q = 0.f;
#pragma unroll
            for (int j = 0; j < 4; ++j) {
                float v = acc[i][j][r] + bia[j];
                if (relu) v = fmaxf(v, 0.f);
                s += v; q += v * v;
            }
#pragma unroll
            for (int o = 1; o < 16; o <<= 1) {
                s += __shfl_xor(s, o);
                q += __shfl_xor(q, o);
            }
            if ((lane & 15) == 0) {
                sS[wn][i * 16 + rq + r] = s;
                sQ[wn][i * 16 + rq + r] = q;
            }
        }
    __syncthreads();
#pragma unroll
    for (int i = 0; i < 2; ++i)
#pragma unroll
        for (int r = 0; r < 4; ++r) {
            const int rl = i * 16 + rq + r;
            const int row = bm + rl;
            const float st = sS[0][rl] + sS[1][rl] + sS[2][rl] + sS[3][rl];
            const float qt = sQ[0][rl] + sQ[1][rl] + sQ[2][rl] + sQ[3][rl];
            const float mean = st * (1.f / 256.f);
            const float var = qt * (1.f / 256.f) - mean * mean;
            const float inv = rsqrtf(var + 1e-5f);
#pragma unroll
            for (int j = 0; j < 4; ++j) {
                const int col = colb + j * 16;
                float v = acc[i][j][r] + bia[j];
                if (relu) v = fmaxf(v, 0.f);
                float o = (v - mean) * inv * gam[j] + bet[j];
                if (MODE >= 1) o += pin[(size_t)row * D_H + col];
                if (MODE == 0)
                    ((float*)outp)[(size_t)row * D_H + col] = o;
                else if (MODE == 1)
                    ((unsigned short*)outp)[(size_t)row * D_H + col] = f2b(o);
                else
                    ((float*)outp)[(size_t)row * D_H + col] = o;
            }
        }
}

// ---------------- weight fp32 -> bf16 (4 arrays, one dispatch) ----------------
__global__ __launch_bounds__(256) void f2b4_kernel(
    const float* __restrict__ s0, unsigned short* __restrict__ d0, int n0,
    const float* __restrict__ s1, unsigned short* __restrict__ d1, int n1,
    const float* __restrict__ s2, unsigned short* __restrict__ d2, int n2,
    const float* __restrict__ s3, unsigned short* __restrict__ d3, int n3)
{
    int i = blockIdx.x * 256 + threadIdx.x;
    const float* s; unsigned short* d;
    if (i < n0) { s = s0; d = d0; }
    else if ((i -= n0) < n1) { s = s1; d = d1; }
    else if ((i -= n1) < n2) { s = s2; d = d2; }
    else if ((i -= n2) < n3) { s = s3; d = d3; }
    else return;
    const float4 v = ((const float4*)s)[i];
    ((ushort4*)d)[i] = make_ushort4(f2b(v.x), f2b(v.y), f2b(v.z), f2b(v.w));
}

// ---------------- CSR build (both etypes batched; once per launch) ----------------
__global__ __launch_bounds__(256) void zero_int_kernel(int* p, int n)
{
    int i = blockIdx.x * 256 + threadIdx.x;
    if (i < n) p[i] = 0;
}

__global__ __launch_bounds__(256) void count_deg_kernel(
    const int* __restrict__ dst, int* __restrict__ cnt, int E2)
{
    int e = blockIdx.x * 256 + threadIdx.x;
    if (e < E2) {
        const int base = (e >= E_EDGES) ? N_NODES : 0;
        atomicAdd(&cnt[base + dst[e]], 1);
    }
}

__global__ __launch_bounds__(256) void scanA_kernel(
    const int* __restrict__ cnt, int* __restrict__ incl, int* __restrict__ bsum, int n)
{
    __shared__ int tmp[256];
    const int tid = threadIdx.x;
    const int i = blockIdx.x * 256 + tid;
    const int v = (i < n) ? cnt[i] : 0;
    tmp[tid] = v;
    __syncthreads();
#pragma unroll
    for (int o = 1; o < 256; o <<= 1) {
        const int t = (tid >= o) ? tmp[tid - o] : 0;
        __syncthreads();
        tmp[tid] += t;
        __syncthreads();
    }
    if (i < n) incl[i] = tmp[tid];
    if (tid == 255) bsum[blockIdx.x] = tmp[255];
}

__global__ __launch_bounds__(256) void scanB_kernel(int* __restrict__ bsum, int nb)
{
    __shared__ int tmp[256];
    const int tid = threadIdx.x;
    const int v = (tid < nb) ? bsum[tid] : 0;
    tmp[tid] = v;
    __syncthreads();
#pragma unroll
    for (int o = 1; o < 256; o <<= 1) {
        const int t = (tid >= o) ? tmp[tid - o] : 0;
        __syncthreads();
        tmp[tid] += t;
        __syncthreads();
    }
    if (tid < nb) bsum[tid] = tmp[tid] - v;  // exclusive
}

__global__ __launch_bounds__(256) void scanC_kernel(
    const int* __restrict__ cnt, const int* __restrict__ incl,
    const int* __restrict__ bsum, int* __restrict__ off, int* __restrict__ cursor, int n)
{
    const int i = blockIdx.x * 256 + threadIdx.x;
    if (i < n) {
        const int e = incl[i] + bsum[blockIdx.x];
        off[i + 1] = e;
        cursor[i] = e - cnt[i];
    }
    if (i == 0) off[0] = 0;
}

__global__ __launch_bounds__(256) void fill_csr_kernel(
    const int* __restrict__ src, const int* __restrict__ dst,
    int* __restrict__ cursor, int* __restrict__ esrc, int E2)
{
    int e = blockIdx.x * 256 + threadIdx.x;
    if (e < E2) {
        const int base = (e >= E_EDGES) ? N_NODES : 0;
        const int pos = atomicAdd(&cursor[base + dst[e]], 1);
        esrc[pos] = src[e];
    }
}

// ---------------- segment max (bf16, both etypes): one wave per (node,t) ----------------
__device__ __forceinline__ ushort4 umax4(ushort4 a, ushort4 b)
{
    a.x = a.x > b.x ? a.x : b.x;
    a.y = a.y > b.y ? a.y : b.y;
    a.z = a.z > b.z ? a.z : b.z;
    a.w = a.w > b.w ? a.w : b.w;
    return a;
}

__global__ __launch_bounds__(256) void seg_max_kernel(
    const unsigned short* __restrict__ hp, const int* __restrict__ off,
    const int* __restrict__ esrc, unsigned short* __restrict__ neigh)
{
    const int g = blockIdx.x * 4 + (threadIdx.x >> 6);
    if (g >= 2 * N_NODES) return;
    const int t = (g >= N_NODES) ? 1 : 0;
    const int node = g - t * N_NODES;
    const int lane = threadIdx.x & 63;
    const int co = t * D_H + lane * 4;
    const int e0 = off[g], e1 = off[g + 1];
    ushort4 acc = make_ushort4(0, 0, 0, 0);
    int e = e0;
    for (; e + 4 <= e1; e += 4) {
        const int s0 = esrc[e + 0], s1 = esrc[e + 1];
        const int s2 = esrc[e + 2], s3 = esrc[e + 3];
        const ushort4 v0 = *(const ushort4*)(hp + (size_t)s0 * 512 + co);
        const ushort4 v1 = *(const ushort4*)(hp + (size_t)s1 * 512 + co);
        const ushort4 v2 = *(const ushort4*)(hp + (size_t)s2 * 512 + co);
        const ushort4 v3 = *(const ushort4*)(hp + (size_t)s3 * 512 + co);
        acc = umax4(umax4(umax4(acc, v0), umax4(v1, v2)), v3);
    }
    for (; e < e1; ++e)
        acc = umax4(acc, *(const ushort4*)(hp + (size_t)esrc[e] * 512 + co));
    *(ushort4*)(neigh + (size_t)node * 512 + co) = acc;
}

extern "C" void kernel_launch(void* const* d_in, const int* in_sizes, int n_in,
                              void* d_out, int out_size, void* d_ws, size_t ws_size,
                              hipStream_t stream)
{
    const float* x      = (const float*)d_in[0];
    const int*   src    = (const int*)d_in[1];
    const int*   dst    = (const int*)d_in[2];
    const float* Wlin   = (const float*)d_in[3];
    const float* blin   = (const float*)d_in[4];
    const float* Wpool  = (const float*)d_in[5];
    const float* bpool  = (const float*)d_in[6];
    const float* Wself  = (const float*)d_in[7];
    const float* Wneigh = (const float*)d_in[8];
    const float* bconv  = (const float*)d_in[9];
    const float* gamma  = (const float*)d_in[10];
    const float* beta   = (const float*)d_in[11];

    const size_t NB = (size_t)N_NODES * D_H;  // 5.12M
    char* p = (char*)d_ws;
    unsigned short* hp_b    = (unsigned short*)p; p += NB * 2 * T_ETYPES;  // [N,512]
    unsigned short* neigh_b = (unsigned short*)p; p += NB * 2 * T_ETYPES;  // [N,512]
    unsigned short* h_a     = (unsigned short*)p; p += NB * 2;
    unsigned short* h_b     = (unsigned short*)p; p += NB * 2;
    float*          partial = (float*)p;          p += NB * 4;
    unsigned short* wlin_b  = (unsigned short*)p; p += (size_t)D_H * F_IN * 2;
    const size_t WSZ = (size_t)L_LAYERS * T_ETYPES * D_H * D_H;
    unsigned short* wpool_b = (unsigned short*)p; p += WSZ * 2;
    unsigned short* wself_b = (unsigned short*)p; p += WSZ * 2;
    unsigned short* wneigh_b= (unsigned short*)p; p += WSZ * 2;
    int* ip = (int*)p;
    const int NT = T_ETYPES * N_NODES;  // 40000
    int* cnt    = ip; ip += NT;
    int* incl   = ip; ip += NT;
    int* off    = ip; ip += NT + 1;
    int* cursor = ip; ip += NT;
    int* esrc   = ip; ip += T_ETYPES * E_EDGES;
    int* bsum   = ip; ip += 256;

    const dim3 blk(256);
    const int E2 = T_ETYPES * E_EDGES;
    const dim3 e2grid((E2 + 255) / 256);
    const dim3 ntgrid((NT + 255) / 256);
    const int nScanBlk = (NT + 255) / 256;  // 157

    // ---- weights -> bf16 (one dispatch) ----
    {
        const int n0 = D_H * F_IN / 4, nw = (int)(WSZ / 4);
        const int tot = n0 + 3 * nw;
        f2b4_kernel<<<dim3((tot + 255) / 256), blk, 0, stream>>>(
            Wlin, wlin_b, n0, Wpool, wpool_b, nw, Wself, wself_b, nw, Wneigh, wneigh_b, nw);
    }

    // ---- CSR build, both etypes batched ----
    zero_int_kernel<<<ntgrid, blk, 0, stream>>>(cnt, NT);
    count_deg_kernel<<<e2grid, blk, 0, stream>>>(dst, cnt, E2);
    scanA_kernel<<<dim3(nScanBlk), blk, 0, stream>>>(cnt, incl, bsum, NT);
    scanB_kernel<<<dim3(1), blk, 0, stream>>>(bsum, nScanBlk);
    scanC_kernel<<<dim3(nScanBlk), blk, 0, stream>>>(cnt, incl, bsum, off, cursor, NT);
    fill_csr_kernel<<<e2grid, blk, 0, stream>>>(src, dst, cursor, esrc, E2);

    // ---- h0 = bf16(x @ Wlin^T + blin) : fp32 A fused-convert ----
    gemm_mfma<1><<<dim3(2, (N_NODES + 63) / 64), blk, 0, stream>>>(
        x, wlin_b, blin, h_a, N_NODES, F_IN, D_H, 0);

    unsigned short* h = h_a;
    unsigned short* hn = h_b;
    const dim3 pgrid(4, (N_NODES + 63) / 64);             // pool: N=512 batched over etypes
    const dim3 sgrid((2 * N_NODES + 3) / 4);
    const dim3 fgrid(N_NODES / 32);                       // 625, exact
    for (int l = 0; l < L_LAYERS; ++l) {
        const int relu = (l < L_LAYERS - 1) ? 1 : 0;
        const size_t wo = (size_t)l * T_ETYPES * D_H * D_H;
        const size_t bo = (size_t)l * T_ETYPES * D_H;
        // hp[:, t*256:] = bf16(relu(h @ Wpool[l,t]^T + bpool[l,t])), both t in one dispatch
        gemm_mfma<0><<<pgrid, blk, 0, stream>>>(
            h, wpool_b + wo, bpool + bo, hp_b, N_NODES, D_H, T_ETYPES * D_H, 1);
        // neigh = segment_max per (node, t)
        seg_max_kernel<<<sgrid, blk, 0, stream>>>(hp_b, off, esrc, neigh_b);
        // fused tail, one etype per dispatch
        for (int t = 0; t < T_ETYPES; ++t) {
            const size_t wot = wo + (size_t)t * D_H * D_H;
            const size_t bot = bo + (size_t)t * D_H;
            if (t == 0) {
                sage_ln32<0><<<fgrid, blk, 0, stream>>>(
                    h, neigh_b, wself_b + wot, wneigh_b + wot,
                    bconv + bot, gamma + bot, beta + bot, nullptr, partial, relu);
            } else if (l < L_LAYERS - 1) {
                sage_ln32<1><<<fgrid, blk, 0, stream>>>(
                    h, neigh_b + t * D_H, wself_b + wot, wneigh_b + wot,
                    bconv + bot, gamma + bot, beta + bot, partial, hn, relu);
            } else {
                sage_ln32<2><<<fgrid, blk, 0, stream>>>(
                    h, neigh_b + t * D_H, wself_b + wot, wneigh_b + wot,
                    bconv + bot, gamma + bot, beta + bot, partial, d_out, relu);
            }
        }
        unsigned short* tmp = h; h = hn; hn = tmp;
    }
}

// Round 7
// 701.723 us; speedup vs baseline: 1.1194x; 1.0434x over previous
//
#include <hip/hip_runtime.h>

// Problem constants (from reference)
#define N_NODES 20000
#define F_IN    512
#define D_H     256
#define E_EDGES 200000
#define L_LAYERS 3
#define T_ETYPES 2

typedef __attribute__((ext_vector_type(8))) short bf16x8;
typedef __attribute__((ext_vector_type(4))) float f32x4;

__device__ __forceinline__ unsigned short f2b(float f) {
    unsigned int u = __float_as_uint(f);
    u = (u + 0x7FFFu + ((u >> 16) & 1u)) >> 16;   // round-nearest-even
    return (unsigned short)u;
}
__device__ __forceinline__ unsigned int pack2(float a, float b) {
    return (unsigned int)f2b(a) | ((unsigned int)f2b(b) << 16);
}

// ---------------- weight pre-shuffle: fp32 row-major -> bf16 fragment-slab order ----
// For W[NO,K] (nmat consecutive matrices): slab (nb0,k0) of 128 rows x 32 k is a
// contiguous 4096-elem block; inside, elem (n_local,kk) at
// ((n_local>>4)&7)<<9 | ((kk>>3)&3)<<7 | (n_local&15)<<3 | (kk&7).
__device__ __forceinline__ void shuf_one(const float* s, unsigned short* d,
                                         int NO, int K, int i)
{
    const int matsz = NO * K;
    const int mat = i / matsz;
    const int rem = i - mat * matsz;
    const int n = rem / K;
    const int k = rem - n * K;
    const int dst = mat * matsz + ((n >> 7) * (K >> 5) + (k >> 5)) * 4096
                  + (((n >> 4) & 7) << 9) + (((k >> 3) & 3) << 7)
                  + ((n & 15) << 3) + (k & 7);
    d[dst] = f2b(s[i]);
}

__global__ __launch_bounds__(256) void shufw_kernel(
    const float* __restrict__ s0, unsigned short* __restrict__ d0, int NO0, int K0, int n0,
    const float* __restrict__ s1, unsigned short* __restrict__ d1, int NO1, int K1, int n1,
    const float* __restrict__ s2, unsigned short* __restrict__ d2, int NO2, int K2, int n2,
    const float* __restrict__ s3, unsigned short* __restrict__ d3, int NO3, int K3, int n3)
{
    int i = blockIdx.x * 256 + threadIdx.x;
    if (i < n0) { shuf_one(s0, d0, NO0, K0, i); return; }
    if ((i -= n0) < n1) { shuf_one(s1, d1, NO1, K1, i); return; }
    if ((i -= n1) < n2) { shuf_one(s2, d2, NO2, K2, i); return; }
    if ((i -= n2) < n3) { shuf_one(s3, d3, NO3, K3, i); return; }
}

// ---------------- GEMM with fragment-slab weights (lin / pool) ----------------
// C[M, bn:bn+128] = act(A @ W^T + bias). Block 64 rows x 128 cols, 4 waves 2x2.
// B staged coalesced from pre-shuffled Wf; A fragments loaded global->VGPR directly.
template <int A_FP32>
__global__ __launch_bounds__(256) void gemm_frag(
    const void* __restrict__ Ap, const unsigned short* __restrict__ Wf,
    const float* __restrict__ bias, unsigned short* __restrict__ Cout,
    int M, int K, int ldc, int relu)
{
    __shared__ unsigned short sB[4096];
    const int tid  = threadIdx.x;
    const int lane = tid & 63;
    const int w    = tid >> 6;
    const int wm   = w >> 1, wn = w & 1;
    const int bm   = blockIdx.y * 64;
    const int bn   = blockIdx.x * 128;
    const int nsteps = K >> 5;
    const unsigned short* slab0 = Wf + (size_t)blockIdx.x * nsteps * 4096;

    const int r0 = min(bm + wm * 32 + (lane & 15), M - 1);
    const int r1 = min(bm + wm * 32 + 16 + (lane & 15), M - 1);
    const int ko = (lane >> 4) << 3;

    f32x4 acc[2][4] = {};

    for (int s = 0; s < nsteps; ++s) {
        const uint4 b0 = *(const uint4*)(slab0 + s * 4096 + tid * 8);
        const uint4 b1 = *(const uint4*)(slab0 + s * 4096 + 2048 + tid * 8);
        bf16x8 af0, af1;
        if (A_FP32) {
            const float* p0 = (const float*)Ap + (size_t)r0 * K + s * 32 + ko;
            const float* p1 = (const float*)Ap + (size_t)r1 * K + s * 32 + ko;
            const float4 a0 = *(const float4*)p0, a1 = *(const float4*)(p0 + 4);
            const float4 a2 = *(const float4*)p1, a3 = *(const float4*)(p1 + 4);
            uint4 u0, u1;
            u0.x = pack2(a0.x, a0.y); u0.y = pack2(a0.z, a0.w);
            u0.z = pack2(a1.x, a1.y); u0.w = pack2(a1.z, a1.w);
            u1.x = pack2(a2.x, a2.y); u1.y = pack2(a2.z, a2.w);
            u1.z = pack2(a3.x, a3.y); u1.w = pack2(a3.z, a3.w);
            af0 = *(bf16x8*)&u0; af1 = *(bf16x8*)&u1;
        } else {
            af0 = *(const bf16x8*)((const unsigned short*)Ap + (size_t)r0 * K + s * 32 + ko);
            af1 = *(const bf16x8*)((const unsigned short*)Ap + (size_t)r1 * K + s * 32 + ko);
        }
        __syncthreads();
        *(uint4*)(sB + tid * 8) = b0;
        *(uint4*)(sB + 2048 + tid * 8) = b1;
        __syncthreads();
#pragma unroll
        for (int j = 0; j < 4; ++j) {
            const bf16x8 bf = *(const bf16x8*)(sB + ((wn * 4 + j) << 9) + lane * 8);
            acc[0][j] = __builtin_amdgcn_mfma_f32_16x16x32_bf16(af0, bf, acc[0][j], 0, 0, 0);
            acc[1][j] = __builtin_amdgcn_mfma_f32_16x16x32_bf16(af1, bf, acc[1][j], 0, 0, 0);
        }
    }

    // C/D layout: col = lane&15, row = (lane>>4)*4 + reg
    const int cbase = bn + wn * 64 + (lane & 15);
    const int rbase = bm + wm * 32 + ((lane >> 4) << 2);
#pragma unroll
    for (int j = 0; j < 4; ++j) {
        const int col = cbase + j * 16;
        const float bj = bias[col];
#pragma unroll
        for (int i = 0; i < 2; ++i)
#pragma unroll
            for (int r = 0; r < 4; ++r) {
                const int row = rbase + i * 16 + r;
                if (row < M) {
                    float v = acc[i][j][r] + bj;
                    if (relu) v = fmaxf(v, 0.f);
                    Cout[(size_t)row * ldc + col] = f2b(v);
                }
            }
    }
}

// ---------------- fused layer tail, ONE etype: dual GEMM + ReLU + LN (+acc) ----------------
// Block 32 rows x 256 cols, 4 waves (wave 32x64), grid 625 exact. Slab-coalesced B,
// direct-from-global A fragments. MODE 0: write fp32 partial. MODE 1: +partial,
// write bf16. MODE 2: +partial, write fp32.
template <int MODE>
__global__ __launch_bounds__(256) void sage_tail(
    const unsigned short* __restrict__ h,      // [M,256] bf16
    const unsigned short* __restrict__ neigh,  // [M,512] bf16 (caller adds t*256)
    const unsigned short* __restrict__ Wfs,    // [2 slabs x 8 steps x 4096]
    const unsigned short* __restrict__ Wfn,
    const float* __restrict__ bias, const float* __restrict__ gamma,
    const float* __restrict__ beta, const float* __restrict__ pin,
    void* __restrict__ outp, int relu)
{
    __shared__ unsigned short sB[8192];
    __shared__ float sS[4][32], sQ[4][32];
    const int tid  = threadIdx.x;
    const int lane = tid & 63;
    const int wn   = tid >> 6;
    const int bm   = blockIdx.x * 32;
    const int r0   = bm + (lane & 15);
    const int r1   = r0 + 16;
    const int ko   = (lane >> 4) << 3;

    f32x4 acc[2][4] = {};

    for (int pass = 0; pass < 2; ++pass) {
        const unsigned short* __restrict__ A = pass ? neigh : h;
        const int lda = pass ? (T_ETYPES * D_H) : D_H;
        const unsigned short* __restrict__ Wf = pass ? Wfn : Wfs;
        for (int s = 0; s < 8; ++s) {
            uint4 b[4];
#pragma unroll
            for (int c = 0; c < 4; ++c) {
                const unsigned short* sl = Wf + (((c >> 1) * 8 + s) << 12);
                b[c] = *(const uint4*)(sl + ((c & 1) << 11) + tid * 8);
            }
            const bf16x8 af0 = *(const bf16x8*)(A + (size_t)r0 * lda + s * 32 + ko);
            const bf16x8 af1 = *(const bf16x8*)(A + (size_t)r1 * lda + s * 32 + ko);
            __syncthreads();
#pragma unroll
            for (int c = 0; c < 4; ++c)
                *(uint4*)(sB + ((c >> 1) << 12) + ((c & 1) << 11) + tid * 8) = b[c];
            __syncthreads();
#pragma unroll
            for (int j = 0; j < 4; ++j) {
                const int t = wn * 4 + j;
                const bf16x8 bf = *(const bf16x8*)(sB + ((t >> 3) << 12) + ((t & 7) << 9) + lane * 8);
                acc[0][j] = __builtin_amdgcn_mfma_f32_16x16x32_bf16(af0, bf, acc[0][j], 0, 0, 0);
                acc[1][j] = __builtin_amdgcn_mfma_f32_16x16x32_bf16(af1, bf, acc[1][j], 0, 0, 0);
            }
        }
    }

    // Epilogue: per-row LN over 256 cols (wave partial over its 64 cols -> LDS combine).
    const int colb = wn * 64 + (lane & 15);
    const int rq   = (lane >> 4) << 2;
    float bia[4], gam[4], bet[4];
#pragma unroll
    for (int j = 0; j < 4; ++j) {
        const int col = colb + j * 16;
        bia[j] = bias[col]; gam[j] = gamma[col]; bet[j] = beta[col];
    }
#pragma unroll
    for (int i = 0; i < 2; ++i)
#pragma unroll
        for (int r = 0; r < 4; ++r) {
            float s = 0.f, q = 0.f;
#pragma unroll
            for (int j = 0; j < 4; ++j) {
                float v = acc[i][j][r] + bia[j];
                if (relu) v = fmaxf(v, 0.f);
                s += v; q += v * v;
            }
#pragma unroll
            for (int o = 1; o < 16; o <<= 1) {
                s += __shfl_xor(s, o);
                q += __shfl_xor(q, o);
            }
            if ((lane & 15) == 0) {
                sS[wn][i * 16 + rq + r] = s;
                sQ[wn][i * 16 + rq + r] = q;
            }
        }
    __syncthreads();
#pragma unroll
    for (int i = 0; i < 2; ++i)
#pragma unroll
        for (int r = 0; r < 4; ++r) {
            const int rl = i * 16 + rq + r;
            const int row = bm + rl;
            const float st = sS[0][rl] + sS[1][rl] + sS[2][rl] + sS[3][rl];
            const float qt = sQ[0][rl] + sQ[1][rl] + sQ[2][rl] + sQ[3][rl];
            const float mean = st * (1.f / 256.f);
            const float var = qt * (1.f / 256.f) - mean * mean;
            const float inv = rsqrtf(var + 1e-5f);
#pragma unroll
            for (int j = 0; j < 4; ++j) {
                const int col = colb + j * 16;
                float v = acc[i][j][r] + bia[j];
                if (relu) v = fmaxf(v, 0.f);
                float o = (v - mean) * inv * gam[j] + bet[j];
                if (MODE >= 1) o += pin[(size_t)row * D_H + col];
                if (MODE == 1)
                    ((unsigned short*)outp)[(size_t)row * D_H + col] = f2b(o);
                else
                    ((float*)outp)[(size_t)row * D_H + col] = o;
            }
        }
}

// ---------------- CSR build (both etypes batched; once per launch) ----------------
__global__ __launch_bounds__(256) void zero_int_kernel(int* p, int n)
{
    int i = blockIdx.x * 256 + threadIdx.x;
    if (i < n) p[i] = 0;
}

__global__ __launch_bounds__(256) void count_deg_kernel(
    const int* __restrict__ dst, int* __restrict__ cnt, int E2)
{
    int e = blockIdx.x * 256 + threadIdx.x;
    if (e < E2) {
        const int base = (e >= E_EDGES) ? N_NODES : 0;
        atomicAdd(&cnt[base + dst[e]], 1);
    }
}

__global__ __launch_bounds__(256) void scanA_kernel(
    const int* __restrict__ cnt, int* __restrict__ incl, int* __restrict__ bsum, int n)
{
    __shared__ int tmp[256];
    const int tid = threadIdx.x;
    const int i = blockIdx.x * 256 + tid;
    const int v = (i < n) ? cnt[i] : 0;
    tmp[tid] = v;
    __syncthreads();
#pragma unroll
    for (int o = 1; o < 256; o <<= 1) {
        const int t = (tid >= o) ? tmp[tid - o] : 0;
        __syncthreads();
        tmp[tid] += t;
        __syncthreads();
    }
    if (i < n) incl[i] = tmp[tid];
    if (tid == 255) bsum[blockIdx.x] = tmp[255];
}

__global__ __launch_bounds__(256) void scanB_kernel(int* __restrict__ bsum, int nb)
{
    __shared__ int tmp[256];
    const int tid = threadIdx.x;
    const int v = (tid < nb) ? bsum[tid] : 0;
    tmp[tid] = v;
    __syncthreads();
#pragma unroll
    for (int o = 1; o < 256; o <<= 1) {
        const int t = (tid >= o) ? tmp[tid - o] : 0;
        __syncthreads();
        tmp[tid] += t;
        __syncthreads();
    }
    if (tid < nb) bsum[tid] = tmp[tid] - v;  // exclusive
}

__global__ __launch_bounds__(256) void scanC_kernel(
    const int* __restrict__ cnt, const int* __restrict__ incl,
    const int* __restrict__ bsum, int* __restrict__ off, int* __restrict__ cursor, int n)
{
    const int i = blockIdx.x * 256 + threadIdx.x;
    if (i < n) {
        const int e = incl[i] + bsum[blockIdx.x];
        off[i + 1] = e;
        cursor[i] = e - cnt[i];
    }
    if (i == 0) off[0] = 0;
}

__global__ __launch_bounds__(256) void fill_csr_kernel(
    const int* __restrict__ src, const int* __restrict__ dst,
    int* __restrict__ cursor, int* __restrict__ esrc, int E2)
{
    int e = blockIdx.x * 256 + threadIdx.x;
    if (e < E2) {
        const int base = (e >= E_EDGES) ? N_NODES : 0;
        const int pos = atomicAdd(&cursor[base + dst[e]], 1);
        esrc[pos] = src[e];
    }
}

// ---------------- segment max (bf16, both etypes): one wave per (node,t) ----------------
__device__ __forceinline__ ushort4 umax4(ushort4 a, ushort4 b)
{
    a.x = a.x > b.x ? a.x : b.x;
    a.y = a.y > b.y ? a.y : b.y;
    a.z = a.z > b.z ? a.z : b.z;
    a.w = a.w > b.w ? a.w : b.w;
    return a;
}

__global__ __launch_bounds__(256) void seg_max_kernel(
    const unsigned short* __restrict__ hp, const int* __restrict__ off,
    const int* __restrict__ esrc, unsigned short* __restrict__ neigh)
{
    const int g = blockIdx.x * 4 + (threadIdx.x >> 6);
    if (g >= 2 * N_NODES) return;
    const int t = (g >= N_NODES) ? 1 : 0;
    const int node = g - t * N_NODES;
    const int lane = threadIdx.x & 63;
    const int co = t * D_H + lane * 4;
    const int e0 = off[g], e1 = off[g + 1];
    ushort4 acc = make_ushort4(0, 0, 0, 0);
    int e = e0;
    for (; e + 4 <= e1; e += 4) {
        const int s0 = esrc[e + 0], s1 = esrc[e + 1];
        const int s2 = esrc[e + 2], s3 = esrc[e + 3];
        const ushort4 v0 = *(const ushort4*)(hp + (size_t)s0 * 512 + co);
        const ushort4 v1 = *(const ushort4*)(hp + (size_t)s1 * 512 + co);
        const ushort4 v2 = *(const ushort4*)(hp + (size_t)s2 * 512 + co);
        const ushort4 v3 = *(const ushort4*)(hp + (size_t)s3 * 512 + co);
        acc = umax4(umax4(umax4(acc, v0), umax4(v1, v2)), v3);
    }
    for (; e < e1; ++e)
        acc = umax4(acc, *(const ushort4*)(hp + (size_t)esrc[e] * 512 + co));
    *(ushort4*)(neigh + (size_t)node * 512 + co) = acc;
}

extern "C" void kernel_launch(void* const* d_in, const int* in_sizes, int n_in,
                              void* d_out, int out_size, void* d_ws, size_t ws_size,
                              hipStream_t stream)
{
    const float* x      = (const float*)d_in[0];
    const int*   src    = (const int*)d_in[1];
    const int*   dst    = (const int*)d_in[2];
    const float* Wlin   = (const float*)d_in[3];
    const float* blin   = (const float*)d_in[4];
    const float* Wpool  = (const float*)d_in[5];
    const float* bpool  = (const float*)d_in[6];
    const float* Wself  = (const float*)d_in[7];
    const float* Wneigh = (const float*)d_in[8];
    const float* bconv  = (const float*)d_in[9];
    const float* gamma  = (const float*)d_in[10];
    const float* beta   = (const float*)d_in[11];

    const size_t NB = (size_t)N_NODES * D_H;  // 5.12M
    char* p = (char*)d_ws;
    unsigned short* hp_b    = (unsigned short*)p; p += NB * 2 * T_ETYPES;  // [N,512]
    unsigned short* neigh_b = (unsigned short*)p; p += NB * 2 * T_ETYPES;  // [N,512]
    unsigned short* h_a     = (unsigned short*)p; p += NB * 2;
    unsigned short* h_b     = (unsigned short*)p; p += NB * 2;
    float*          partial = (float*)p;          p += NB * 4;
    unsigned short* wlin_f  = (unsigned short*)p; p += (size_t)D_H * F_IN * 2;
    const size_t WSZ = (size_t)L_LAYERS * T_ETYPES * D_H * D_H;  // 393216
    unsigned short* wpool_f = (unsigned short*)p; p += WSZ * 2;
    unsigned short* wself_f = (unsigned short*)p; p += WSZ * 2;
    unsigned short* wneigh_f= (unsigned short*)p; p += WSZ * 2;
    int* ip = (int*)p;
    const int NT = T_ETYPES * N_NODES;  // 40000
    int* cnt    = ip; ip += NT;
    int* incl   = ip; ip += NT;
    int* off    = ip; ip += NT + 1;
    int* cursor = ip; ip += NT;
    int* esrc   = ip; ip += T_ETYPES * E_EDGES;
    int* bsum   = ip; ip += 256;

    const dim3 blk(256);
    const int E2 = T_ETYPES * E_EDGES;
    const dim3 e2grid((E2 + 255) / 256);
    const dim3 ntgrid((NT + 255) / 256);
    const int nScanBlk = (NT + 255) / 256;  // 157

    // ---- weights -> bf16 fragment-slab order (one dispatch) ----
    {
        const int nlin = D_H * F_IN;          // 131072, NO=256 K=512
        const int nw   = (int)WSZ;            // 393216
        const int tot  = nlin + 3 * nw;
        shufw_kernel<<<dim3((tot + 255) / 256), blk, 0, stream>>>(
            Wlin, wlin_f, D_H, F_IN, nlin,
            Wpool, wpool_f, T_ETYPES * D_H, D_H, nw,   // per layer: [512,256]
            Wself, wself_f, D_H, D_H, nw,              // per (l,t): [256,256]
            Wneigh, wneigh_f, D_H, D_H, nw);
    }

    // ---- CSR build, both etypes batched ----
    zero_int_kernel<<<ntgrid, blk, 0, stream>>>(cnt, NT);
    count_deg_kernel<<<e2grid, blk, 0, stream>>>(dst, cnt, E2);
    scanA_kernel<<<dim3(nScanBlk), blk, 0, stream>>>(cnt, incl, bsum, NT);
    scanB_kernel<<<dim3(1), blk, 0, stream>>>(bsum, nScanBlk);
    scanC_kernel<<<dim3(nScanBlk), blk, 0, stream>>>(cnt, incl, bsum, off, cursor, NT);
    fill_csr_kernel<<<e2grid, blk, 0, stream>>>(src, dst, cursor, esrc, E2);

    // ---- h0 = bf16(x @ Wlin^T + blin) : fp32 A fused-convert ----
    gemm_frag<1><<<dim3(2, (N_NODES + 63) / 64), blk, 0, stream>>>(
        x, wlin_f, blin, h_a, N_NODES, F_IN, D_H, 0);

    unsigned short* h = h_a;
    unsigned short* hn = h_b;
    const dim3 pgrid(4, (N_NODES + 63) / 64);   // pool: 512 cols batched over etypes
    const dim3 sgrid((2 * N_NODES + 3) / 4);
    const dim3 fgrid(N_NODES / 32);             // 625, exact
    for (int l = 0; l < L_LAYERS; ++l) {
        const int relu = (l < L_LAYERS - 1) ? 1 : 0;
        // hp[:, t*256:] = bf16(relu(h @ Wpool[l,t]^T + bpool[l,t])), both t in one dispatch
        gemm_frag<0><<<pgrid, blk, 0, stream>>>(
            h, wpool_f + (size_t)l * T_ETYPES * D_H * D_H, bpool + (size_t)l * T_ETYPES * D_H,
            hp_b, N_NODES, D_H, T_ETYPES * D_H, 1);
        // neigh = segment_max per (node, t)
        seg_max_kernel<<<sgrid, blk, 0, stream>>>(hp_b, off, esrc, neigh_b);
        // fused tail, one etype per dispatch
        for (int t = 0; t < T_ETYPES; ++t) {
            const size_t wot = ((size_t)l * T_ETYPES + t) * D_H * D_H;
            const size_t bot = ((size_t)l * T_ETYPES + t) * D_H;
            if (t == 0) {
                sage_tail<0><<<fgrid, blk, 0, stream>>>(
                    h, neigh_b, wself_f + wot, wneigh_f + wot,
                    bconv + bot, gamma + bot, beta + bot, nullptr, partial, relu);
            } else if (l < L_LAYERS - 1) {
                sage_tail<1><<<fgrid, blk, 0, stream>>>(
                    h, neigh_b + t * D_H, wself_f + wot, wneigh_f + wot,
                    bconv + bot, gamma + bot, beta + bot, partial, hn, relu);
            } else {
                sage_tail<2><<<fgrid, blk, 0, stream>>>(
                    h, neigh_b + t * D_H, wself_f + wot, wneigh_f + wot,
                    bconv + bot, gamma + bot, beta + bot, partial, d_out, relu);
            }
        }
        unsigned short* tmp = h; h = hn; hn = tmp;
    }
}

// Round 8
// 523.312 us; speedup vs baseline: 1.5010x; 1.3409x over previous
//
#include <hip/hip_runtime.h>

// Problem constants (from reference)
#define N_NODES 20000
#define F_IN    512
#define D_H     256
#define E_EDGES 200000
#define L_LAYERS 3
#define T_ETYPES 2

typedef __attribute__((ext_vector_type(8))) short bf16x8;
typedef __attribute__((ext_vector_type(4))) float f32x4;

__device__ __forceinline__ unsigned short f2b(float f) {
    unsigned int u = __float_as_uint(f);
    u = (u + 0x7FFFu + ((u >> 16) & 1u)) >> 16;   // round-nearest-even
    return (unsigned short)u;
}
__device__ __forceinline__ unsigned int pack2(float a, float b) {
    return (unsigned int)f2b(a) | ((unsigned int)f2b(b) << 16);
}

// ---------------- weight pre-shuffle: fp32 row-major -> bf16 fragment-slab order ----
// For W[NO,K]: slab (n>>7, k>>5) of 128 rows x 32 k is a contiguous 4096-elem block;
// inside, elem (n_local,kk) at ((n_local>>4)&7)<<9 | ((kk>>3)&3)<<7 | (n_local&15)<<3 | (kk&7).
// A wave's 16x32 B-tile t at step s is then the 1KB run: slab + (t&7)*512 + lane*8.
__device__ __forceinline__ void shuf_one(const float* s, unsigned short* d,
                                         int NO, int K, int i)
{
    const int matsz = NO * K;
    const int mat = i / matsz;
    const int rem = i - mat * matsz;
    const int n = rem / K;
    const int k = rem - n * K;
    const int dst = mat * matsz + ((n >> 7) * (K >> 5) + (k >> 5)) * 4096
                  + (((n >> 4) & 7) << 9) + (((k >> 3) & 3) << 7)
                  + ((n & 15) << 3) + (k & 7);
    d[dst] = f2b(s[i]);
}

__global__ __launch_bounds__(256) void shufw_kernel(
    const float* __restrict__ s0, unsigned short* __restrict__ d0, int NO0, int K0, int n0,
    const float* __restrict__ s1, unsigned short* __restrict__ d1, int NO1, int K1, int n1,
    const float* __restrict__ s2, unsigned short* __restrict__ d2, int NO2, int K2, int n2,
    const float* __restrict__ s3, unsigned short* __restrict__ d3, int NO3, int K3, int n3)
{
    int i = blockIdx.x * 256 + threadIdx.x;
    if (i < n0) { shuf_one(s0, d0, NO0, K0, i); return; }
    if ((i -= n0) < n1) { shuf_one(s1, d1, NO1, K1, i); return; }
    if ((i -= n1) < n2) { shuf_one(s2, d2, NO2, K2, i); return; }
    if ((i -= n2) < n3) { shuf_one(s3, d3, NO3, K3, i); return; }
}

// ---------------- barrier-free GEMM, fragment-slab weights (lin / pool) ----------------
// C[M, bn:bn+128] = act(A @ W^T + bias). Block 64x128, 4 waves 2x2, wave 32x64.
// NO LDS, NO barriers: A and B fragments both stream global->VGPR (B coalesced 1KB/inst).
template <int A_FP32, int NSTEPS>
__global__ __launch_bounds__(256) void gemm_frag(
    const void* __restrict__ Ap, const unsigned short* __restrict__ Wf,
    const float* __restrict__ bias, unsigned short* __restrict__ Cout,
    int M, int ldc, int relu)
{
    const int K = NSTEPS * 32;
    const int tid  = threadIdx.x;
    const int lane = tid & 63;
    const int w    = tid >> 6;
    const int wm   = w >> 1, wn = w & 1;
    const int bm   = blockIdx.y * 64;
    const int bn   = blockIdx.x * 128;
    const unsigned short* slab0 = Wf + (size_t)blockIdx.x * NSTEPS * 4096;

    const int r0 = min(bm + wm * 32 + (lane & 15), M - 1);
    const int r1 = min(bm + wm * 32 + 16 + (lane & 15), M - 1);
    const int ko = (lane >> 4) << 3;

    f32x4 acc[2][4] = {};

    for (int s = 0; s < NSTEPS; ++s) {
        bf16x8 af0, af1;
        if (A_FP32) {
            const float* p0 = (const float*)Ap + (size_t)r0 * K + s * 32 + ko;
            const float* p1 = (const float*)Ap + (size_t)r1 * K + s * 32 + ko;
            const float4 a0 = *(const float4*)p0, a1 = *(const float4*)(p0 + 4);
            const float4 a2 = *(const float4*)p1, a3 = *(const float4*)(p1 + 4);
            uint4 u0, u1;
            u0.x = pack2(a0.x, a0.y); u0.y = pack2(a0.z, a0.w);
            u0.z = pack2(a1.x, a1.y); u0.w = pack2(a1.z, a1.w);
            u1.x = pack2(a2.x, a2.y); u1.y = pack2(a2.z, a2.w);
            u1.z = pack2(a3.x, a3.y); u1.w = pack2(a3.z, a3.w);
            af0 = *(bf16x8*)&u0; af1 = *(bf16x8*)&u1;
        } else {
            af0 = *(const bf16x8*)((const unsigned short*)Ap + (size_t)r0 * K + s * 32 + ko);
            af1 = *(const bf16x8*)((const unsigned short*)Ap + (size_t)r1 * K + s * 32 + ko);
        }
#pragma unroll
        for (int j = 0; j < 4; ++j) {
            const bf16x8 bf = *(const bf16x8*)(slab0 + s * 4096 + ((wn * 4 + j) << 9) + lane * 8);
            acc[0][j] = __builtin_amdgcn_mfma_f32_16x16x32_bf16(af0, bf, acc[0][j], 0, 0, 0);
            acc[1][j] = __builtin_amdgcn_mfma_f32_16x16x32_bf16(af1, bf, acc[1][j], 0, 0, 0);
        }
    }

    // C/D layout: col = lane&15, row = (lane>>4)*4 + reg
    const int cbase = bn + wn * 64 + (lane & 15);
    const int rbase = bm + wm * 32 + ((lane >> 4) << 2);
#pragma unroll
    for (int j = 0; j < 4; ++j) {
        const int col = cbase + j * 16;
        const float bj = bias[col];
#pragma unroll
        for (int i = 0; i < 2; ++i)
#pragma unroll
            for (int r = 0; r < 4; ++r) {
                const int row = rbase + i * 16 + r;
                if (row < M) {
                    float v = acc[i][j][r] + bj;
                    if (relu) v = fmaxf(v, 0.f);
                    Cout[(size_t)row * ldc + col] = f2b(v);
                }
            }
    }
}

// ---------------- fused layer tail, ONE etype: dual GEMM + ReLU + LN (+acc) ----------------
// Block 32 rows x 256 cols, 4 waves (wave 32x64), grid 625 exact. Barrier-free K-loop:
// A and B both stream global->VGPR. One barrier only in the LN epilogue.
// MODE 0: write fp32 partial. MODE 1: +partial, write bf16. MODE 2: +partial, write fp32.
template <int MODE>
__global__ __launch_bounds__(256) void sage_tail(
    const unsigned short* __restrict__ h,      // [M,256] bf16
    const unsigned short* __restrict__ neigh,  // [M,512] bf16 (caller adds t*256)
    const unsigned short* __restrict__ Wfs,    // [2 slabs x 8 steps x 4096]
    const unsigned short* __restrict__ Wfn,
    const float* __restrict__ bias, const float* __restrict__ gamma,
    const float* __restrict__ beta, const float* __restrict__ pin,
    void* __restrict__ outp, int relu)
{
    __shared__ float sS[4][32], sQ[4][32];
    const int tid  = threadIdx.x;
    const int lane = tid & 63;
    const int wn   = tid >> 6;
    const int bm   = blockIdx.x * 32;
    const int r0   = bm + (lane & 15);
    const int r1   = r0 + 16;
    const int ko   = (lane >> 4) << 3;

    f32x4 acc[2][4] = {};

    for (int pass = 0; pass < 2; ++pass) {
        const unsigned short* __restrict__ A = pass ? neigh : h;
        const int lda = pass ? (T_ETYPES * D_H) : D_H;
        const unsigned short* __restrict__ Wf = pass ? Wfn : Wfs;
#pragma unroll 2
        for (int s = 0; s < 8; ++s) {
            const bf16x8 af0 = *(const bf16x8*)(A + (size_t)r0 * lda + s * 32 + ko);
            const bf16x8 af1 = *(const bf16x8*)(A + (size_t)r1 * lda + s * 32 + ko);
#pragma unroll
            for (int j = 0; j < 4; ++j) {
                const int t = wn * 4 + j;                       // tile 0..7 over 2 slabs? no: 0..7 within wn span
                const int tt = t;                                // tiles 0..15 across 2 slabs handled below
                const unsigned short* bp = Wf + (((tt >> 3) * 8 + s) << 12) + ((tt & 7) << 9) + lane * 8;
                const bf16x8 bf = *(const bf16x8*)bp;
                acc[0][j] = __builtin_amdgcn_mfma_f32_16x16x32_bf16(af0, bf, acc[0][j], 0, 0, 0);
                acc[1][j] = __builtin_amdgcn_mfma_f32_16x16x32_bf16(af1, bf, acc[1][j], 0, 0, 0);
            }
        }
    }

    // Epilogue: per-row LN over 256 cols (wave partial over its 64 cols -> LDS combine).
    const int colb = wn * 64 + (lane & 15);
    const int rq   = (lane >> 4) << 2;
    float bia[4], gam[4], bet[4];
#pragma unroll
    for (int j = 0; j < 4; ++j) {
        const int col = colb + j * 16;
        bia[j] = bias[col]; gam[j] = gamma[col]; bet[j] = beta[col];
    }
#pragma unroll
    for (int i = 0; i < 2; ++i)
#pragma unroll
        for (int r = 0; r < 4; ++r) {
            float s = 0.f, q = 0.f;
#pragma unroll
            for (int j = 0; j < 4; ++j) {
                float v = acc[i][j][r] + bia[j];
                if (relu) v = fmaxf(v, 0.f);
                s += v; q += v * v;
            }
#pragma unroll
            for (int o = 1; o < 16; o <<= 1) {
                s += __shfl_xor(s, o);
                q += __shfl_xor(q, o);
            }
            if ((lane & 15) == 0) {
                sS[wn][i * 16 + rq + r] = s;
                sQ[wn][i * 16 + rq + r] = q;
            }
        }
    __syncthreads();
#pragma unroll
    for (int i = 0; i < 2; ++i)
#pragma unroll
        for (int r = 0; r < 4; ++r) {
            const int rl = i * 16 + rq + r;
            const int row = bm + rl;
            const float st = sS[0][rl] + sS[1][rl] + sS[2][rl] + sS[3][rl];
            const float qt = sQ[0][rl] + sQ[1][rl] + sQ[2][rl] + sQ[3][rl];
            const float mean = st * (1.f / 256.f);
            const float var = qt * (1.f / 256.f) - mean * mean;
            const float inv = rsqrtf(var + 1e-5f);
#pragma unroll
            for (int j = 0; j < 4; ++j) {
                const int col = colb + j * 16;
                float v = acc[i][j][r] + bia[j];
                if (relu) v = fmaxf(v, 0.f);
                float o = (v - mean) * inv * gam[j] + bet[j];
                if (MODE >= 1) o += pin[(size_t)row * D_H + col];
                if (MODE == 1)
                    ((unsigned short*)outp)[(size_t)row * D_H + col] = f2b(o);
                else
                    ((float*)outp)[(size_t)row * D_H + col] = o;
            }
        }
}

// Note on the tail's B tile index: wave wn covers cols wn*64..wn*64+63 -> tiles wn*4+j
// (0..7), all within slab (t>>3). With 256 cols = 16 tiles the high tiles (8..15) belong
// to waves wn=2,3 whose t = wn*4+j >= 8 select slab 1 via (t>>3). Correct as written.

// ---------------- CSR build (both etypes batched; once per launch) ----------------
__global__ __launch_bounds__(256) void zero_int_kernel(int* p, int n)
{
    int i = blockIdx.x * 256 + threadIdx.x;
    if (i < n) p[i] = 0;
}

__global__ __launch_bounds__(256) void count_deg_kernel(
    const int* __restrict__ dst, int* __restrict__ cnt, int E2)
{
    int e = blockIdx.x * 256 + threadIdx.x;
    if (e < E2) {
        const int base = (e >= E_EDGES) ? N_NODES : 0;
        atomicAdd(&cnt[base + dst[e]], 1);
    }
}

__global__ __launch_bounds__(256) void scanA_kernel(
    const int* __restrict__ cnt, int* __restrict__ incl, int* __restrict__ bsum, int n)
{
    __shared__ int tmp[256];
    const int tid = threadIdx.x;
    const int i = blockIdx.x * 256 + tid;
    const int v = (i < n) ? cnt[i] : 0;
    tmp[tid] = v;
    __syncthreads();
#pragma unroll
    for (int o = 1; o < 256; o <<= 1) {
        const int t = (tid >= o) ? tmp[tid - o] : 0;
        __syncthreads();
        tmp[tid] += t;
        __syncthreads();
    }
    if (i < n) incl[i] = tmp[tid];
    if (tid == 255) bsum[blockIdx.x] = tmp[255];
}

__global__ __launch_bounds__(256) void scanB_kernel(int* __restrict__ bsum, int nb)
{
    __shared__ int tmp[256];
    const int tid = threadIdx.x;
    const int v = (tid < nb) ? bsum[tid] : 0;
    tmp[tid] = v;
    __syncthreads();
#pragma unroll
    for (int o = 1; o < 256; o <<= 1) {
        const int t = (tid >= o) ? tmp[tid - o] : 0;
        __syncthreads();
        tmp[tid] += t;
        __syncthreads();
    }
    if (tid < nb) bsum[tid] = tmp[tid] - v;  // exclusive
}

__global__ __launch_bounds__(256) void scanC_kernel(
    const int* __restrict__ cnt, const int* __restrict__ incl,
    const int* __restrict__ bsum, int* __restrict__ off, int* __restrict__ cursor, int n)
{
    const int i = blockIdx.x * 256 + threadIdx.x;
    if (i < n) {
        const int e = incl[i] + bsum[blockIdx.x];
        off[i + 1] = e;
        cursor[i] = e - cnt[i];
    }
    if (i == 0) off[0] = 0;
}

__global__ __launch_bounds__(256) void fill_csr_kernel(
    const int* __restrict__ src, const int* __restrict__ dst,
    int* __restrict__ cursor, int* __restrict__ esrc, int E2)
{
    int e = blockIdx.x * 256 + threadIdx.x;
    if (e < E2) {
        const int base = (e >= E_EDGES) ? N_NODES : 0;
        const int pos = atomicAdd(&cursor[base + dst[e]], 1);
        esrc[pos] = src[e];
    }
}

// ---------------- segment max (bf16, both etypes): one wave per (node,t) ----------------
__device__ __forceinline__ ushort4 umax4(ushort4 a, ushort4 b)
{
    a.x = a.x > b.x ? a.x : b.x;
    a.y = a.y > b.y ? a.y : b.y;
    a.z = a.z > b.z ? a.z : b.z;
    a.w = a.w > b.w ? a.w : b.w;
    return a;
}

__global__ __launch_bounds__(256) void seg_max_kernel(
    const unsigned short* __restrict__ hp, const int* __restrict__ off,
    const int* __restrict__ esrc, unsigned short* __restrict__ neigh)
{
    const int g = blockIdx.x * 4 + (threadIdx.x >> 6);
    if (g >= 2 * N_NODES) return;
    const int t = (g >= N_NODES) ? 1 : 0;
    const int node = g - t * N_NODES;
    const int lane = threadIdx.x & 63;
    const int co = t * D_H + lane * 4;
    const int e0 = off[g], e1 = off[g + 1];
    ushort4 acc = make_ushort4(0, 0, 0, 0);
    int e = e0;
    for (; e + 4 <= e1; e += 4) {
        const int s0 = esrc[e + 0], s1 = esrc[e + 1];
        const int s2 = esrc[e + 2], s3 = esrc[e + 3];
        const ushort4 v0 = *(const ushort4*)(hp + (size_t)s0 * 512 + co);
        const ushort4 v1 = *(const ushort4*)(hp + (size_t)s1 * 512 + co);
        const ushort4 v2 = *(const ushort4*)(hp + (size_t)s2 * 512 + co);
        const ushort4 v3 = *(const ushort4*)(hp + (size_t)s3 * 512 + co);
        acc = umax4(umax4(umax4(acc, v0), umax4(v1, v2)), v3);
    }
    for (; e < e1; ++e)
        acc = umax4(acc, *(const ushort4*)(hp + (size_t)esrc[e] * 512 + co));
    *(ushort4*)(neigh + (size_t)node * 512 + co) = acc;
}

extern "C" void kernel_launch(void* const* d_in, const int* in_sizes, int n_in,
                              void* d_out, int out_size, void* d_ws, size_t ws_size,
                              hipStream_t stream)
{
    const float* x      = (const float*)d_in[0];
    const int*   src    = (const int*)d_in[1];
    const int*   dst    = (const int*)d_in[2];
    const float* Wlin   = (const float*)d_in[3];
    const float* blin   = (const float*)d_in[4];
    const float* Wpool  = (const float*)d_in[5];
    const float* bpool  = (const float*)d_in[6];
    const float* Wself  = (const float*)d_in[7];
    const float* Wneigh = (const float*)d_in[8];
    const float* bconv  = (const float*)d_in[9];
    const float* gamma  = (const float*)d_in[10];
    const float* beta   = (const float*)d_in[11];

    const size_t NB = (size_t)N_NODES * D_H;  // 5.12M
    char* p = (char*)d_ws;
    unsigned short* hp_b    = (unsigned short*)p; p += NB * 2 * T_ETYPES;  // [N,512]
    unsigned short* neigh_b = (unsigned short*)p; p += NB * 2 * T_ETYPES;  // [N,512]
    unsigned short* h_a     = (unsigned short*)p; p += NB * 2;
    unsigned short* h_b     = (unsigned short*)p; p += NB * 2;
    float*          partial = (float*)p;          p += NB * 4;
    unsigned short* wlin_f  = (unsigned short*)p; p += (size_t)D_H * F_IN * 2;
    const size_t WSZ = (size_t)L_LAYERS * T_ETYPES * D_H * D_H;  // 393216
    unsigned short* wpool_f = (unsigned short*)p; p += WSZ * 2;
    unsigned short* wself_f = (unsigned short*)p; p += WSZ * 2;
    unsigned short* wneigh_f= (unsigned short*)p; p += WSZ * 2;
    int* ip = (int*)p;
    const int NT = T_ETYPES * N_NODES;  // 40000
    int* cnt    = ip; ip += NT;
    int* incl   = ip; ip += NT;
    int* off    = ip; ip += NT + 1;
    int* cursor = ip; ip += NT;
    int* esrc   = ip; ip += T_ETYPES * E_EDGES;
    int* bsum   = ip; ip += 256;

    const dim3 blk(256);
    const int E2 = T_ETYPES * E_EDGES;
    const dim3 e2grid((E2 + 255) / 256);
    const dim3 ntgrid((NT + 255) / 256);
    const int nScanBlk = (NT + 255) / 256;  // 157

    // ---- weights -> bf16 fragment-slab order (one dispatch) ----
    {
        const int nlin = D_H * F_IN;          // 131072, NO=256 K=512
        const int nw   = (int)WSZ;            // 393216
        const int tot  = nlin + 3 * nw;
        shufw_kernel<<<dim3((tot + 255) / 256), blk, 0, stream>>>(
            Wlin, wlin_f, D_H, F_IN, nlin,
            Wpool, wpool_f, T_ETYPES * D_H, D_H, nw,   // per layer: [512,256]
            Wself, wself_f, D_H, D_H, nw,              // per (l,t): [256,256]
            Wneigh, wneigh_f, D_H, D_H, nw);
    }

    // ---- CSR build, both etypes batched ----
    zero_int_kernel<<<ntgrid, blk, 0, stream>>>(cnt, NT);
    count_deg_kernel<<<e2grid, blk, 0, stream>>>(dst, cnt, E2);
    scanA_kernel<<<dim3(nScanBlk), blk, 0, stream>>>(cnt, incl, bsum, NT);
    scanB_kernel<<<dim3(1), blk, 0, stream>>>(bsum, nScanBlk);
    scanC_kernel<<<dim3(nScanBlk), blk, 0, stream>>>(cnt, incl, bsum, off, cursor, NT);
    fill_csr_kernel<<<e2grid, blk, 0, stream>>>(src, dst, cursor, esrc, E2);

    // ---- h0 = bf16(x @ Wlin^T + blin) : fp32 A fused-convert, K=512 ----
    gemm_frag<1, 16><<<dim3(2, (N_NODES + 63) / 64), blk, 0, stream>>>(
        x, wlin_f, blin, h_a, N_NODES, D_H, 0);

    unsigned short* h = h_a;
    unsigned short* hn = h_b;
    const dim3 pgrid(4, (N_NODES + 63) / 64);   // pool: 512 cols batched over etypes
    const dim3 sgrid((2 * N_NODES + 3) / 4);
    const dim3 fgrid(N_NODES / 32);             // 625, exact
    for (int l = 0; l < L_LAYERS; ++l) {
        const int relu = (l < L_LAYERS - 1) ? 1 : 0;
        // hp[:, t*256:] = bf16(relu(h @ Wpool[l,t]^T + bpool[l,t])), both t in one dispatch
        gemm_frag<0, 8><<<pgrid, blk, 0, stream>>>(
            h, wpool_f + (size_t)l * T_ETYPES * D_H * D_H, bpool + (size_t)l * T_ETYPES * D_H,
            hp_b, N_NODES, T_ETYPES * D_H, 1);
        // neigh = segment_max per (node, t)
        seg_max_kernel<<<sgrid, blk, 0, stream>>>(hp_b, off, esrc, neigh_b);
        // fused tail, one etype per dispatch
        for (int t = 0; t < T_ETYPES; ++t) {
            const size_t wot = ((size_t)l * T_ETYPES + t) * D_H * D_H;
            const size_t bot = ((size_t)l * T_ETYPES + t) * D_H;
            if (t == 0) {
                sage_tail<0><<<fgrid, blk, 0, stream>>>(
                    h, neigh_b, wself_f + wot, wneigh_f + wot,
                    bconv + bot, gamma + bot, beta + bot, nullptr, partial, relu);
            } else if (l < L_LAYERS - 1) {
                sage_tail<1><<<fgrid, blk, 0, stream>>>(
                    h, neigh_b + t * D_H, wself_f + wot, wneigh_f + wot,
                    bconv + bot, gamma + bot, beta + bot, partial, hn, relu);
            } else {
                sage_tail<2><<<fgrid, blk, 0, stream>>>(
                    h, neigh_b + t * D_H, wself_f + wot, wneigh_f + wot,
                    bconv + bot, gamma + bot, beta + bot, partial, d_out, relu);
            }
        }
        unsigned short* tmp = h; h = hn; hn = tmp;
    }
}